// Round 4
// baseline (641.333 us; speedup 1.0000x reference)
//
#include <hip/hip_runtime.h>
#include <hip/hip_bf16.h>
#include <stdint.h>

// ---------- types ----------
using bf16x8 = __attribute__((ext_vector_type(8))) __bf16;
using s16x8  = __attribute__((ext_vector_type(8))) short;
using f32x4  = __attribute__((ext_vector_type(4))) float;

__device__ __forceinline__ uint16_t f2bf(float f) {
    uint32_t u = __builtin_bit_cast(uint32_t, f);
    u += 0x7fffu + ((u >> 16) & 1u);   // RNE
    return (uint16_t)(u >> 16);
}
__device__ __forceinline__ float bf2f(uint16_t h) {
    return __builtin_bit_cast(float, (uint32_t)h << 16);
}

__device__ __forceinline__ void async16(uint16_t* lds_dst, const uint16_t* g_src) {
    __builtin_amdgcn_global_load_lds(
        (const __attribute__((address_space(1))) void*)g_src,
        (__attribute__((address_space(3))) void*)lds_dst,
        16, 0, 0);
}

// ---------- K0: transpose + f32->bf16 convert (weights) ----------
__global__ void tconv_k(const float* __restrict__ in, uint16_t* __restrict__ out,
                        int R, int C) {
    int idx = blockIdx.x * 256 + threadIdx.x;
    if (idx >= R * C) return;
    int r = idx / C, c = idx - r * C;
    out[(long)c * R + r] = f2bf(in[idx]);
}

// ---------- K0b: x f32 -> bf16 ----------
__global__ void xconv_k(const float* __restrict__ in, uint16_t* __restrict__ out) {
    long base = ((long)blockIdx.x * 256 + threadIdx.x) * 8;
    float4 v0 = *(const float4*)(in + base);
    float4 v1 = *(const float4*)(in + base + 4);
    uint16_t t[8];
    t[0] = f2bf(v0.x); t[1] = f2bf(v0.y); t[2] = f2bf(v0.z); t[3] = f2bf(v0.w);
    t[4] = f2bf(v1.x); t[5] = f2bf(v1.y); t[6] = f2bf(v1.z); t[7] = f2bf(v1.w);
    *(s16x8*)(out + base) = *(const s16x8*)t;
}

// ---------- g4: 256x256 tile, BK=32, 4-buf, reg-frag software pipeline ----------
// Per tile: {stage t+3 | vmcnt(8)+lgkm(0) | barrier | ds_read frags(t+1) | 32 MFMA(t)}.
// ds_reads of t+1 overlap MFMA of t (no dependency); one barrier/tile.
template<bool OUTF32>
__global__ __launch_bounds__(512, 2)
void g4_k(const uint16_t* __restrict__ A, const uint16_t* __restrict__ Bt,
          void* __restrict__ Cp, const float* __restrict__ bias,
          int K, int lda, int ldb, int ldc, int mtiles, int ntiles,
          long abr, long bbe, long cbr)
{
    __shared__ uint16_t lds[65536];   // 4 bufs x (A 8192 + B 8192) elems = 128 KiB
    const int tid  = threadIdx.x;
    const int lane = tid & 63;
    const int wv   = tid >> 6;
    const int wr   = wv >> 2, wc = wv & 3;

    // XCD-aware bijective swizzle (grids %8==0)
    const int q8 = gridDim.x >> 3;
    const int l  = (blockIdx.x & 7) * q8 + (blockIdx.x >> 3);
    const int per   = mtiles * ntiles;
    const int batch = l / per;
    const int rem   = l - batch * per;
    const int mt    = rem / ntiles, nt = rem - mt * ntiles;

    const long arow0 = abr * batch + (long)mt * 256;
    const uint16_t* btb = Bt + bbe * batch + (long)nt * 256 * ldb;

    const int srs = lane >> 2;
    const int scp = lane & 3;
    const int fr  = lane & 15;
    const int fc  = (lane >> 4) ^ ((fr >> 1) & 3);
    const int aoff = (wr * 128 + fr) * 32 + fc * 8;
    const int boff = (wc * 64  + fr) * 32 + fc * 8;

    const int NT = K >> 5;

    auto stageA = [&](int bsel, int k0) {
#pragma unroll
        for (int i = 0; i < 2; ++i) {
            int r = i * 128 + wv * 16 + srs;
            int c = scp ^ ((r >> 1) & 3);
            async16(&lds[bsel * 16384 + i * 4096 + wv * 512],
                    A + (arow0 + r) * (long)lda + (k0 + c * 8));
        }
    };
    auto stageB = [&](int bsel, int k0) {
#pragma unroll
        for (int i = 0; i < 2; ++i) {
            int r = i * 128 + wv * 16 + srs;
            int c = scp ^ ((r >> 1) & 3);
            async16(&lds[bsel * 16384 + 8192 + i * 4096 + wv * 512],
                    btb + (long)r * ldb + (k0 + c * 8));
        }
    };

    f32x4 acc[8][4];
#pragma unroll
    for (int m = 0; m < 8; ++m)
#pragma unroll
        for (int n = 0; n < 4; ++n) acc[m][n] = (f32x4){0.f, 0.f, 0.f, 0.f};

    bf16x8 Ra0[8], Rb0[4], Ra1[8], Rb1[4];

    // prologue: tiles 0,1,2 in flight; drain tile 0; preload frags(0) into R0.
    stageA(0, 0);  stageB(0, 0);
    stageA(1, 32); stageB(1, 32);
    stageA(2, 64); stageB(2, 64);
    asm volatile("s_waitcnt vmcnt(8)" ::: "memory");
    __builtin_amdgcn_sched_barrier(0);
    __builtin_amdgcn_s_barrier();
    __builtin_amdgcn_sched_barrier(0);
#pragma unroll
    for (int m = 0; m < 8; ++m)
        Ra0[m] = __builtin_bit_cast(bf16x8, *(const s16x8*)&lds[aoff + m * 512]);
#pragma unroll
    for (int n = 0; n < 4; ++n)
        Rb0[n] = __builtin_bit_cast(bf16x8, *(const s16x8*)&lds[8192 + boff + n * 512]);

    auto body = [&](int t, bf16x8 (&Ca)[8], bf16x8 (&Cb)[4],
                    bf16x8 (&Na)[8], bf16x8 (&Nb)[4]) {
        if (t + 3 < NT) {
            int bsel = (t + 3) & 3, k0 = (t + 3) << 5;
            stageA(bsel, k0);
            stageB(bsel, k0);
        }
        if (t + 3 < NT)      asm volatile("s_waitcnt vmcnt(8)" ::: "memory");
        else if (t + 2 < NT) asm volatile("s_waitcnt vmcnt(4)" ::: "memory");
        else                 asm volatile("s_waitcnt vmcnt(0)" ::: "memory");
        asm volatile("s_waitcnt lgkmcnt(0)" ::: "memory");
        __builtin_amdgcn_sched_barrier(0);
        __builtin_amdgcn_s_barrier();
        __builtin_amdgcn_sched_barrier(0);
        if (t + 1 < NT) {
            const uint16_t* Ab = &lds[((t + 1) & 3) * 16384];
            const uint16_t* Bb = Ab + 8192;
#pragma unroll
            for (int m = 0; m < 8; ++m)
                Na[m] = __builtin_bit_cast(bf16x8, *(const s16x8*)&Ab[aoff + m * 512]);
#pragma unroll
            for (int n = 0; n < 4; ++n)
                Nb[n] = __builtin_bit_cast(bf16x8, *(const s16x8*)&Bb[boff + n * 512]);
        }
        __builtin_amdgcn_s_setprio(1);
#pragma unroll
        for (int m = 0; m < 8; ++m)
#pragma unroll
            for (int n = 0; n < 4; ++n)
                acc[m][n] = __builtin_amdgcn_mfma_f32_16x16x32_bf16(
                    Ca[m], Cb[n], acc[m][n], 0, 0, 0);
        // pin interleave: {3 ds_read, 8 mfma} x 4 within this scheduling region
#pragma unroll
        for (int g = 0; g < 4; ++g) {
            __builtin_amdgcn_sched_group_barrier(0x100, 3, 0);  // DS_READ
            __builtin_amdgcn_sched_group_barrier(0x008, 8, 0);  // MFMA
        }
        __builtin_amdgcn_s_setprio(0);
    };

    for (int t = 0; t < NT; t += 2) {
        body(t,     Ra0, Rb0, Ra1, Rb1);
        body(t + 1, Ra1, Rb1, Ra0, Rb0);
    }

    // ---- epilogue: D row=(lane>>4)*4+r, col=lane&15 ----
    const long crow0 = cbr * batch + (long)mt * 256 + wr * 128;
    const int  col0  = nt * 256 + wc * 64;
    float bv[4];
#pragma unroll
    for (int n = 0; n < 4; ++n)
        bv[n] = bias ? bias[col0 + n * 16 + (lane & 15)] : 0.f;
#pragma unroll
    for (int m = 0; m < 8; ++m) {
#pragma unroll
        for (int r = 0; r < 4; ++r) {
            long row = crow0 + m * 16 + (lane >> 4) * 4 + r;
#pragma unroll
            for (int n = 0; n < 4; ++n) {
                int col = col0 + n * 16 + (lane & 15);
                float v = acc[m][n][r];
                if constexpr (OUTF32)
                    ((float*)Cp)[row * (long)ldc + col] = v + bv[n];
                else
                    ((uint16_t*)Cp)[row * (long)ldc + col] = f2bf(v);
            }
        }
    }
}

// ---------- K3a: partial sim over a 1024-wide d segment ----------
__global__ __launch_bounds__(256, 2)
void sim_part_k(const uint16_t* __restrict__ qkv, float* __restrict__ simP)
{
    __shared__ float qs[64 * 64];
    __shared__ float ksh[64 * 64];
    __shared__ float red[64 * 64];
    const int tid = threadIdx.x;
    const int bh = blockIdx.x >> 2, seg = blockIdx.x & 3;
    const int b = bh >> 3, h = bh & 7;
    const int ds = tid >> 6;
    const int tj = (tid >> 3) & 7;
    const int ti = tid & 7;
    const uint16_t* qb = qkv + (long)b * 4096 * 1536 + h * 64;
    const uint16_t* kb = qb + 512;

    float acc[8][8];
#pragma unroll
    for (int a = 0; a < 8; ++a)
#pragma unroll
        for (int c = 0; c < 8; ++c) acc[a][c] = 0.f;

    for (int c0 = seg * 1024; c0 < seg * 1024 + 1024; c0 += 64) {
#pragma unroll
        for (int it = 0; it < 2; ++it) {
            int e = it * 2048 + tid * 8;
            int dd = e >> 6, i = e & 63;
            s16x8 v = *(const s16x8*)(qb + (long)(c0 + dd) * 1536 + i);
#pragma unroll
            for (int u = 0; u < 8; ++u) qs[dd * 64 + i + u] = bf2f((uint16_t)v[u]);
            v = *(const s16x8*)(kb + (long)(c0 + dd) * 1536 + i);
#pragma unroll
            for (int u = 0; u < 8; ++u) ksh[dd * 64 + i + u] = bf2f((uint16_t)v[u]);
        }
        __syncthreads();
        for (int dd = ds * 16; dd < ds * 16 + 16; ++dd) {
            float qa[8], ka[8];
            *(float4*)&qa[0] = *(const float4*)&qs[dd * 64 + ti * 8];
            *(float4*)&qa[4] = *(const float4*)&qs[dd * 64 + ti * 8 + 4];
            *(float4*)&ka[0] = *(const float4*)&ksh[dd * 64 + tj * 8];
            *(float4*)&ka[4] = *(const float4*)&ksh[dd * 64 + tj * 8 + 4];
#pragma unroll
            for (int a = 0; a < 8; ++a)
#pragma unroll
                for (int c = 0; c < 8; ++c)
                    acc[a][c] = fmaf(qa[a], ka[c], acc[a][c]);
        }
        __syncthreads();
    }
    for (int w = 0; w < 4; ++w) {
        if (ds == w) {
#pragma unroll
            for (int a = 0; a < 8; ++a)
#pragma unroll
                for (int c = 0; c < 8; ++c) {
                    float* p = &red[(ti * 8 + a) * 64 + tj * 8 + c];
                    *p = (w == 0) ? acc[a][c] : (*p + acc[a][c]);
                }
        }
        __syncthreads();
    }
    float* o = simP + (long)blockIdx.x * 4096;
#pragma unroll
    for (int u = 0; u < 4; ++u)
        ((float4*)o)[tid * 4 + u] = ((const float4*)red)[tid * 4 + u];
}

// ---------- K3b: sum 4 partials + softmax -> attnT[j][i] bf16 ----------
__global__ __launch_bounds__(256, 4)
void softmax_k(const float* __restrict__ simP, uint16_t* __restrict__ attnT)
{
    __shared__ float rtmp[64 * 4];
    const int tid = threadIdx.x;
    const int i = tid >> 2, jc = tid & 3;
    const float* base = simP + (long)blockIdx.x * 4 * 4096;
    float s[16];
#pragma unroll
    for (int j = 0; j < 16; ++j) {
        float acc = 0.f;
#pragma unroll
        for (int seg = 0; seg < 4; ++seg)
            acc += base[seg * 4096 + i * 64 + jc * 16 + j];
        s[j] = acc * 0.125f;
    }
    float mx = s[0];
#pragma unroll
    for (int j = 1; j < 16; ++j) mx = fmaxf(mx, s[j]);
    rtmp[i * 4 + jc] = mx;
    __syncthreads();
    float m4 = fmaxf(fmaxf(rtmp[i * 4], rtmp[i * 4 + 1]),
                     fmaxf(rtmp[i * 4 + 2], rtmp[i * 4 + 3]));
    float sum = 0.f;
#pragma unroll
    for (int j = 0; j < 16; ++j) { s[j] = __expf(s[j] - m4); sum += s[j]; }
    __syncthreads();
    rtmp[i * 4 + jc] = sum;
    __syncthreads();
    float tot = rtmp[i * 4] + rtmp[i * 4 + 1] + rtmp[i * 4 + 2] + rtmp[i * 4 + 3];
    float inv = 1.f / tot;
    uint16_t* at = attnT + (long)blockIdx.x * 4096;
#pragma unroll
    for (int j = 0; j < 16; ++j)
        at[(jc * 16 + j) * 64 + i] = f2bf(s[j] * inv);
}

// ---------- K4: W2T[b][c][h*64+j] = sum_i attn[i][j]*w_out[h*64+i][c] ----------
__global__ __launch_bounds__(256, 1)
void w2_k(const uint16_t* __restrict__ attnT, const uint16_t* __restrict__ woutT,
          uint16_t* __restrict__ W2T)
{
    const int tid = threadIdx.x;
    const int lane = tid & 63, wv = tid >> 6;
    const int b = blockIdx.x >> 3, h = blockIdx.x & 7;
    const uint16_t* at = attnT + (long)blockIdx.x * 4096;

    bf16x8 bfrag[2][4];
#pragma unroll
    for (int ks = 0; ks < 2; ++ks)
#pragma unroll
        for (int nf = 0; nf < 4; ++nf) {
            s16x8 v = *(const s16x8*)&at[(nf * 16 + (lane & 15)) * 64 + ks * 32 + (lane >> 4) * 8];
            bfrag[ks][nf] = __builtin_bit_cast(bf16x8, v);
        }
    f32x4 acc[8][4];
#pragma unroll
    for (int mf = 0; mf < 8; ++mf)
#pragma unroll
        for (int nf = 0; nf < 4; ++nf) acc[mf][nf] = (f32x4){0.f, 0.f, 0.f, 0.f};
#pragma unroll
    for (int mf = 0; mf < 8; ++mf) {
        int c = wv * 128 + mf * 16 + (lane & 15);
#pragma unroll
        for (int ks = 0; ks < 2; ++ks) {
            s16x8 v = *(const s16x8*)&woutT[(long)c * 512 + h * 64 + ks * 32 + (lane >> 4) * 8];
            bf16x8 af = __builtin_bit_cast(bf16x8, v);
#pragma unroll
            for (int nf = 0; nf < 4; ++nf)
                acc[mf][nf] = __builtin_amdgcn_mfma_f32_16x16x32_bf16(
                    af, bfrag[ks][nf], acc[mf][nf], 0, 0, 0);
        }
    }
    uint16_t* o = W2T + (long)b * 512 * 512;
#pragma unroll
    for (int mf = 0; mf < 8; ++mf)
#pragma unroll
        for (int nf = 0; nf < 4; ++nf)
#pragma unroll
            for (int r = 0; r < 4; ++r) {
                int c = wv * 128 + mf * 16 + (lane >> 4) * 4 + r;
                int j = nf * 16 + (lane & 15);
                o[(long)c * 512 + h * 64 + j] = f2bf(acc[mf][nf][r]);
            }
}

// ---------- launcher ----------
extern "C" void kernel_launch(void* const* d_in, const int* in_sizes, int n_in,
                              void* d_out, int out_size, void* d_ws, size_t ws_size,
                              hipStream_t stream)
{
    const float* x     = (const float*)d_in[0];
    const float* w_qkv = (const float*)d_in[1];
    const float* w_out = (const float*)d_in[2];
    const float* b_out = (const float*)d_in[3];
    float* out = (float*)d_out;

    char* ws = (char*)d_ws;
    uint16_t* qkv   = (uint16_t*)(ws);                   // 402,653,184 B
    uint16_t* wqkvT = (uint16_t*)(ws + 402653184L);      // 1,572,864 B
    uint16_t* woutT = (uint16_t*)(ws + 404226048L);      // 524,288 B
    uint16_t* attnT = (uint16_t*)(ws + 404750336L);      // 2,097,152 B
    float*    simP  = (float*)(ws + 406847488L);         // aliases W2T (simP dead first)
    uint16_t* W2T   = (uint16_t*)(ws + 406847488L);      // 16,777,216 B

    // xb (bf16 x) lives in d_out: dead before GEMM2 overwrites d_out.
    uint16_t* xb = (uint16_t*)d_out;

    tconv_k<<<(512 * 1536) / 256, 256, 0, stream>>>(w_qkv, wqkvT, 512, 1536);
    tconv_k<<<(512 * 512) / 256, 256, 0, stream>>>(w_out, woutT, 512, 512);
    xconv_k<<<32768, 256, 0, stream>>>(x, xb);

    // GEMM1: qkv = xb @ wqkvT^T -> bf16 [131072][1536]
    g4_k<false><<<3072, 512, 0, stream>>>(
        xb, wqkvT, qkv, nullptr,
        512, 512, 512, 1536, 512, 6, 0L, 0L, 0L);

    // sim partials (4-way split-K over d) + softmax
    sim_part_k<<<1024, 256, 0, stream>>>(qkv, simP);
    softmax_k<<<256, 256, 0, stream>>>(simP, attnT);

    // per-batch effective projection weights (transposed)
    w2_k<<<256, 256, 0, stream>>>(attnT, woutT, W2T);

    // GEMM2: out[b] = v[b] @ W2T[b]^T + b_out
    g4_k<true><<<1024, 512, 0, stream>>>(
        qkv + 1024, W2T, out, b_out,
        512, 1536, 512, 512, 16, 2,
        4096L, 262144L, 4096L);
}

// Round 5
// 575.258 us; speedup vs baseline: 1.1149x; 1.1149x over previous
//
#include <hip/hip_runtime.h>
#include <hip/hip_bf16.h>
#include <stdint.h>

// ---------- types ----------
using bf16x8 = __attribute__((ext_vector_type(8))) __bf16;
using s16x8  = __attribute__((ext_vector_type(8))) short;
using f32x4  = __attribute__((ext_vector_type(4))) float;

__device__ __forceinline__ uint16_t f2bf(float f) {
    uint32_t u = __builtin_bit_cast(uint32_t, f);
    u += 0x7fffu + ((u >> 16) & 1u);   // RNE
    return (uint16_t)(u >> 16);
}
__device__ __forceinline__ float bf2f(uint16_t h) {
    return __builtin_bit_cast(float, (uint32_t)h << 16);
}

__device__ __forceinline__ void async16(uint16_t* lds_dst, const uint16_t* g_src) {
    __builtin_amdgcn_global_load_lds(
        (const __attribute__((address_space(1))) void*)g_src,
        (__attribute__((address_space(3))) void*)lds_dst,
        16, 0, 0);
}

// ---------- K0: transpose + f32->bf16 convert (weights) ----------
__global__ void tconv_k(const float* __restrict__ in, uint16_t* __restrict__ out,
                        int R, int C) {
    int idx = blockIdx.x * 256 + threadIdx.x;
    if (idx >= R * C) return;
    int r = idx / C, c = idx - r * C;
    out[(long)c * R + r] = f2bf(in[idx]);
}

// ---------- K0b: x f32 -> bf16 ----------
__global__ void xconv_k(const float* __restrict__ in, uint16_t* __restrict__ out) {
    long base = ((long)blockIdx.x * 256 + threadIdx.x) * 8;
    float4 v0 = *(const float4*)(in + base);
    float4 v1 = *(const float4*)(in + base + 4);
    uint16_t t[8];
    t[0] = f2bf(v0.x); t[1] = f2bf(v0.y); t[2] = f2bf(v0.z); t[3] = f2bf(v0.w);
    t[4] = f2bf(v1.x); t[5] = f2bf(v1.y); t[6] = f2bf(v1.z); t[7] = f2bf(v1.w);
    *(s16x8*)(out + base) = *(const s16x8*)t;
}

// ---------- g8: 256x256 tile, BK=64, 8-phase counted-vmcnt (m201-style) ----------
// 512 thr = 8 waves (2M x 4N), per-wave 128x64 out. LDS = 8 half-slots x 16KB.
// Tile t: even -> slots 0-3 (A0,A1,B0,B1), odd -> slots 4-7.
// Phase q=(mhalf,ks) per K-tile: reads 8/4/8/4 ds_read_b128; 16 MFMA each.
// Stages: ph0: O.A01 | ph3: (E+2).B01 | ph4: (E+2).A01 | ph7: (O+2).B01.
// vmcnt(4) checkpoints at ph3/ph7 (tail: vmcnt(0)).
template<bool OUTF32>
__global__ __launch_bounds__(512, 2)
void g8_k(const uint16_t* __restrict__ A, const uint16_t* __restrict__ Bt,
          void* __restrict__ Cp, const float* __restrict__ bias,
          int K, int lda, int ldb, int ldc, int mtiles, int ntiles,
          long abr, long bbe, long cbr)
{
    __shared__ uint16_t lds[65536];   // 128 KiB
    const int tid  = threadIdx.x;
    const int lane = tid & 63;
    const int wv   = tid >> 6;
    const int wr   = wv >> 2, wc = wv & 3;

    // XCD-aware bijective swizzle (grids %8==0)
    const int q8 = gridDim.x >> 3;
    const int l  = (blockIdx.x & 7) * q8 + (blockIdx.x >> 3);
    const int per   = mtiles * ntiles;
    const int batch = l / per;
    const int rem   = l - batch * per;
    const int mt    = rem / ntiles, nt = rem - mt * ntiles;

    const long arow0 = abr * batch + (long)mt * 256;
    const uint16_t* abase = A + arow0 * (long)lda;
    const uint16_t* btb   = Bt + bbe * batch + (long)nt * 256 * ldb;

    const int fr = lane & 15;
    // per-lane constant swizzled chunk slot, per ks (r&7 == fr&7 for all frag rows)
    const int cx0 = (((0 << 2) | (lane >> 4)) ^ (fr & 7)) * 8;
    const int cx1 = (((1 << 2) | (lane >> 4)) ^ (fr & 7)) * 8;
    // per-lane frag base offsets (elements)
    const int baseA = wr * 8192 + fr * 64;                    // + b4*8192 + m*1024 + cx
    const int baseB = (2 + (wc >> 1)) * 8192 + ((wc & 1) * 64 + fr) * 64;  // + b4*8192 + n*1024 + cx

    const int NT = K >> 6;

    // stage one 128x64 half into slot; gb = row0 of half; pre-swizzled source
    auto stage = [&](int slot, const uint16_t* gb, int rstride, int k0) {
#pragma unroll
        for (int i = 0; i < 2; ++i) {
            int si = i * 512 + wv * 64 + lane;
            int rr = si >> 3, cc = (si & 7) ^ (rr & 7);
            async16(&lds[slot * 8192 + (i * 512 + wv * 64) * 8],
                    gb + (long)rr * rstride + k0 + cc * 8);
        }
    };

    f32x4 acc[8][4];
#pragma unroll
    for (int m = 0; m < 8; ++m)
#pragma unroll
        for (int n = 0; n < 4; ++n) acc[m][n] = (f32x4){0.f, 0.f, 0.f, 0.f};

    bf16x8 af[4], bfq[4];

    auto rdA = [&](int mb, int b4, int cx) {
#pragma unroll
        for (int mi = 0; mi < 4; ++mi)
            af[mi] = __builtin_bit_cast(bf16x8,
                *(const s16x8*)&lds[b4 * 8192 + baseA + (mb + mi) * 1024 + cx]);
    };
    auto rdB = [&](int b4, int cx) {
#pragma unroll
        for (int n = 0; n < 4; ++n)
            bfq[n] = __builtin_bit_cast(bf16x8,
                *(const s16x8*)&lds[b4 * 8192 + baseB + n * 1024 + cx]);
    };
    auto mm = [&](int mb) {
        asm volatile("s_waitcnt lgkmcnt(0)" ::: "memory");
        __builtin_amdgcn_sched_barrier(0);
        __builtin_amdgcn_s_setprio(1);
#pragma unroll
        for (int mi = 0; mi < 4; ++mi)
#pragma unroll
            for (int n = 0; n < 4; ++n)
                acc[mb + mi][n] = __builtin_amdgcn_mfma_f32_16x16x32_bf16(
                    af[mi], bfq[n], acc[mb + mi][n], 0, 0, 0);
        __builtin_amdgcn_s_setprio(0);
        __builtin_amdgcn_s_barrier();   // barrier2
    };

    // ---- prologue: T0 {A0,A1,B0,B1} -> slots 0-3 ; T1 {B0,B1} -> slots 6,7 ----
    stage(0, abase,              lda, 0);
    stage(1, abase + 128L * lda, lda, 0);
    stage(2, btb,                ldb, 0);
    stage(3, btb + 128L * ldb,   ldb, 0);
    stage(6, btb,                ldb, 64);
    stage(7, btb + 128L * ldb,   ldb, 64);
    asm volatile("s_waitcnt vmcnt(4)" ::: "memory");   // T0 landed; T1.B in flight
    __builtin_amdgcn_sched_barrier(0);
    __builtin_amdgcn_s_barrier();

    for (int it = 0; it < (NT >> 1); ++it) {
        const int E = 2 * it, Od = E + 1;
        const bool s3 = (E + 2) < NT;
        const bool s7 = (Od + 2) < NT;
        const int kE2 = (E + 2) << 6, kO1 = Od << 6, kO2 = (Od + 2) << 6;

        // ---- ph0: E q(m0-3,ks0); stage O.A01 -> slots 4,5 ----
        rdB(0, cx0); rdA(0, 0, cx0);
        stage(4, abase,              lda, kO1);
        stage(5, abase + 128L * lda, lda, kO1);
        __builtin_amdgcn_s_barrier();
        mm(0);
        // ---- ph1: E q(m4-7,ks0) ----
        rdA(4, 0, cx0);
        __builtin_amdgcn_s_barrier();
        mm(4);
        // ---- ph2: E q(m0-3,ks1) ----
        rdB(0, cx1); rdA(0, 0, cx1);
        __builtin_amdgcn_s_barrier();
        mm(0);
        // ---- ph3: E q(m4-7,ks1); stage (E+2).B01 -> slots 2,3; vmcnt ----
        rdA(4, 0, cx1);
        if (s3) {
            stage(2, btb,              ldb, kE2);
            stage(3, btb + 128L * ldb, ldb, kE2);
            asm volatile("s_waitcnt vmcnt(4)" ::: "memory");
        } else {
            asm volatile("s_waitcnt vmcnt(0)" ::: "memory");
        }
        __builtin_amdgcn_sched_barrier(0);
        __builtin_amdgcn_s_barrier();
        mm(4);
        // ---- ph4: O q(m0-3,ks0); stage (E+2).A01 -> slots 0,1 ----
        rdB(4, cx0); rdA(0, 4, cx0);
        if (s3) {
            stage(0, abase,              lda, kE2);
            stage(1, abase + 128L * lda, lda, kE2);
        }
        __builtin_amdgcn_s_barrier();
        mm(0);
        // ---- ph5: O q(m4-7,ks0) ----
        rdA(4, 4, cx0);
        __builtin_amdgcn_s_barrier();
        mm(4);
        // ---- ph6: O q(m0-3,ks1) ----
        rdB(4, cx1); rdA(0, 4, cx1);
        __builtin_amdgcn_s_barrier();
        mm(0);
        // ---- ph7: O q(m4-7,ks1); stage (O+2).B01 -> slots 6,7; vmcnt ----
        rdA(4, 4, cx1);
        if (s7) {
            stage(6, btb,              ldb, kO2);
            stage(7, btb + 128L * ldb, ldb, kO2);
            asm volatile("s_waitcnt vmcnt(4)" ::: "memory");
        } else {
            asm volatile("s_waitcnt vmcnt(0)" ::: "memory");
        }
        __builtin_amdgcn_sched_barrier(0);
        __builtin_amdgcn_s_barrier();
        mm(4);
    }

    // ---- epilogue: D row=(lane>>4)*4+r, col=lane&15 ----
    const long crow0 = cbr * batch + (long)mt * 256 + wr * 128;
    const int  col0  = nt * 256 + wc * 64;
    float bv[4];
#pragma unroll
    for (int n = 0; n < 4; ++n)
        bv[n] = bias ? bias[col0 + n * 16 + (lane & 15)] : 0.f;
#pragma unroll
    for (int m = 0; m < 8; ++m) {
#pragma unroll
        for (int r = 0; r < 4; ++r) {
            long row = crow0 + m * 16 + (lane >> 4) * 4 + r;
#pragma unroll
            for (int n = 0; n < 4; ++n) {
                int col = col0 + n * 16 + (lane & 15);
                float v = acc[m][n][r];
                if constexpr (OUTF32)
                    ((float*)Cp)[row * (long)ldc + col] = v + bv[n];
                else
                    ((uint16_t*)Cp)[row * (long)ldc + col] = f2bf(v);
            }
        }
    }
}

// ---------- K3a: partial sim over a 1024-wide d segment ----------
__global__ __launch_bounds__(256, 4)
void sim_part_k(const uint16_t* __restrict__ qkv, float* __restrict__ simP)
{
    __shared__ float qs[64 * 64];
    __shared__ float ksh[64 * 64];
    float* red = qs;   // reuse: qs dead after last c0 iteration
    const int tid = threadIdx.x;
    const int bh = blockIdx.x >> 2, seg = blockIdx.x & 3;
    const int b = bh >> 3, h = bh & 7;
    const int ds = tid >> 6;
    const int tj = (tid >> 3) & 7;
    const int ti = tid & 7;
    const uint16_t* qb = qkv + (long)b * 4096 * 1536 + h * 64;
    const uint16_t* kb = qb + 512;

    float acc[8][8];
#pragma unroll
    for (int a = 0; a < 8; ++a)
#pragma unroll
        for (int c = 0; c < 8; ++c) acc[a][c] = 0.f;

    for (int c0 = seg * 1024; c0 < seg * 1024 + 1024; c0 += 64) {
#pragma unroll
        for (int it = 0; it < 2; ++it) {
            int e = it * 2048 + tid * 8;
            int dd = e >> 6, i = e & 63;
            s16x8 v = *(const s16x8*)(qb + (long)(c0 + dd) * 1536 + i);
#pragma unroll
            for (int u = 0; u < 8; ++u) qs[dd * 64 + i + u] = bf2f((uint16_t)v[u]);
            v = *(const s16x8*)(kb + (long)(c0 + dd) * 1536 + i);
#pragma unroll
            for (int u = 0; u < 8; ++u) ksh[dd * 64 + i + u] = bf2f((uint16_t)v[u]);
        }
        __syncthreads();
        for (int dd = ds * 16; dd < ds * 16 + 16; ++dd) {
            float qa[8], ka[8];
            *(float4*)&qa[0] = *(const float4*)&qs[dd * 64 + ti * 8];
            *(float4*)&qa[4] = *(const float4*)&qs[dd * 64 + ti * 8 + 4];
            *(float4*)&ka[0] = *(const float4*)&ksh[dd * 64 + tj * 8];
            *(float4*)&ka[4] = *(const float4*)&ksh[dd * 64 + tj * 8 + 4];
#pragma unroll
            for (int a = 0; a < 8; ++a)
#pragma unroll
                for (int c = 0; c < 8; ++c)
                    acc[a][c] = fmaf(qa[a], ka[c], acc[a][c]);
        }
        __syncthreads();
    }
    for (int w = 0; w < 4; ++w) {
        if (ds == w) {
#pragma unroll
            for (int a = 0; a < 8; ++a)
#pragma unroll
                for (int c = 0; c < 8; ++c) {
                    float* p = &red[(ti * 8 + a) * 64 + tj * 8 + c];
                    *p = (w == 0) ? acc[a][c] : (*p + acc[a][c]);
                }
        }
        __syncthreads();
    }
    float* o = simP + (long)blockIdx.x * 4096;
#pragma unroll
    for (int u = 0; u < 4; ++u)
        ((float4*)o)[tid * 4 + u] = ((const float4*)red)[tid * 4 + u];
}

// ---------- K3b: sum 4 partials + softmax -> attnT[j][i] bf16 ----------
__global__ __launch_bounds__(256, 4)
void softmax_k(const float* __restrict__ simP, uint16_t* __restrict__ attnT)
{
    __shared__ float rtmp[64 * 4];
    const int tid = threadIdx.x;
    const int i = tid >> 2, jc = tid & 3;
    const float* base = simP + (long)blockIdx.x * 4 * 4096;
    float s[16];
#pragma unroll
    for (int j = 0; j < 16; ++j) {
        float acc = 0.f;
#pragma unroll
        for (int seg = 0; seg < 4; ++seg)
            acc += base[seg * 4096 + i * 64 + jc * 16 + j];
        s[j] = acc * 0.125f;
    }
    float mx = s[0];
#pragma unroll
    for (int j = 1; j < 16; ++j) mx = fmaxf(mx, s[j]);
    rtmp[i * 4 + jc] = mx;
    __syncthreads();
    float m4 = fmaxf(fmaxf(rtmp[i * 4], rtmp[i * 4 + 1]),
                     fmaxf(rtmp[i * 4 + 2], rtmp[i * 4 + 3]));
    float sum = 0.f;
#pragma unroll
    for (int j = 0; j < 16; ++j) { s[j] = __expf(s[j] - m4); sum += s[j]; }
    __syncthreads();
    rtmp[i * 4 + jc] = sum;
    __syncthreads();
    float tot = rtmp[i * 4] + rtmp[i * 4 + 1] + rtmp[i * 4 + 2] + rtmp[i * 4 + 3];
    float inv = 1.f / tot;
    uint16_t* at = attnT + (long)blockIdx.x * 4096;
#pragma unroll
    for (int j = 0; j < 16; ++j)
        at[(jc * 16 + j) * 64 + i] = f2bf(s[j] * inv);
}

// ---------- K4: W2T[b][c][h*64+j] = sum_i attn[i][j]*w_out[h*64+i][c] ----------
__global__ __launch_bounds__(256, 1)
void w2_k(const uint16_t* __restrict__ attnT, const uint16_t* __restrict__ woutT,
          uint16_t* __restrict__ W2T)
{
    const int tid = threadIdx.x;
    const int lane = tid & 63, wv = tid >> 6;
    const int b = blockIdx.x >> 3, h = blockIdx.x & 7;
    const uint16_t* at = attnT + (long)blockIdx.x * 4096;

    bf16x8 bfrag[2][4];
#pragma unroll
    for (int ks = 0; ks < 2; ++ks)
#pragma unroll
        for (int nf = 0; nf < 4; ++nf) {
            s16x8 v = *(const s16x8*)&at[(nf * 16 + (lane & 15)) * 64 + ks * 32 + (lane >> 4) * 8];
            bfrag[ks][nf] = __builtin_bit_cast(bf16x8, v);
        }
    f32x4 acc[8][4];
#pragma unroll
    for (int mf = 0; mf < 8; ++mf)
#pragma unroll
        for (int nf = 0; nf < 4; ++nf) acc[mf][nf] = (f32x4){0.f, 0.f, 0.f, 0.f};
#pragma unroll
    for (int mf = 0; mf < 8; ++mf) {
        int c = wv * 128 + mf * 16 + (lane & 15);
#pragma unroll
        for (int ks = 0; ks < 2; ++ks) {
            s16x8 v = *(const s16x8*)&woutT[(long)c * 512 + h * 64 + ks * 32 + (lane >> 4) * 8];
            bf16x8 af = __builtin_bit_cast(bf16x8, v);
#pragma unroll
            for (int nf = 0; nf < 4; ++nf)
                acc[mf][nf] = __builtin_amdgcn_mfma_f32_16x16x32_bf16(
                    af, bfrag[ks][nf], acc[mf][nf], 0, 0, 0);
        }
    }
    uint16_t* o = W2T + (long)b * 512 * 512;
#pragma unroll
    for (int mf = 0; mf < 8; ++mf)
#pragma unroll
        for (int nf = 0; nf < 4; ++nf)
#pragma unroll
            for (int r = 0; r < 4; ++r) {
                int c = wv * 128 + mf * 16 + (lane >> 4) * 4 + r;
                int j = nf * 16 + (lane & 15);
                o[(long)c * 512 + h * 64 + j] = f2bf(acc[mf][nf][r]);
            }
}

// ---------- launcher ----------
extern "C" void kernel_launch(void* const* d_in, const int* in_sizes, int n_in,
                              void* d_out, int out_size, void* d_ws, size_t ws_size,
                              hipStream_t stream)
{
    const float* x     = (const float*)d_in[0];
    const float* w_qkv = (const float*)d_in[1];
    const float* w_out = (const float*)d_in[2];
    const float* b_out = (const float*)d_in[3];
    float* out = (float*)d_out;

    char* ws = (char*)d_ws;
    uint16_t* qkv   = (uint16_t*)(ws);                   // 402,653,184 B
    uint16_t* wqkvT = (uint16_t*)(ws + 402653184L);      // 1,572,864 B
    uint16_t* woutT = (uint16_t*)(ws + 404226048L);      // 524,288 B
    uint16_t* attnT = (uint16_t*)(ws + 404750336L);      // 2,097,152 B
    float*    simP  = (float*)(ws + 406847488L);         // aliases W2T (simP dead first)
    uint16_t* W2T   = (uint16_t*)(ws + 406847488L);      // 16,777,216 B

    // xb (bf16 x) lives in d_out: dead before GEMM2 overwrites d_out.
    uint16_t* xb = (uint16_t*)d_out;

    tconv_k<<<(512 * 1536) / 256, 256, 0, stream>>>(w_qkv, wqkvT, 512, 1536);
    tconv_k<<<(512 * 512) / 256, 256, 0, stream>>>(w_out, woutT, 512, 512);
    xconv_k<<<32768, 256, 0, stream>>>(x, xb);

    // GEMM1: qkv = xb @ wqkvT^T -> bf16 [131072][1536]
    g8_k<false><<<3072, 512, 0, stream>>>(
        xb, wqkvT, qkv, nullptr,
        512, 512, 512, 1536, 512, 6, 0L, 0L, 0L);

    // sim partials (4-way split-K over d) + softmax
    sim_part_k<<<1024, 256, 0, stream>>>(qkv, simP);
    softmax_k<<<256, 256, 0, stream>>>(simP, attnT);

    // per-batch effective projection weights (transposed)
    w2_k<<<256, 256, 0, stream>>>(attnT, woutT, W2T);

    // GEMM2: out[b] = v[b] @ W2T[b]^T + b_out
    g8_k<true><<<1024, 512, 0, stream>>>(
        qkv + 1024, W2T, out, b_out,
        512, 1536, 512, 512, 16, 2,
        4096L, 262144L, 4096L);
}

// Round 7
// 382.095 us; speedup vs baseline: 1.6785x; 1.5055x over previous
//
#include <hip/hip_runtime.h>
#include <hip/hip_bf16.h>
#include <stdint.h>

// ---------- types ----------
using bf16x8 = __attribute__((ext_vector_type(8))) __bf16;
using s16x8  = __attribute__((ext_vector_type(8))) short;
using f32x4  = __attribute__((ext_vector_type(4))) float;

__device__ __forceinline__ uint16_t f2bf(float f) {
    uint32_t u = __builtin_bit_cast(uint32_t, f);
    u += 0x7fffu + ((u >> 16) & 1u);   // RNE
    return (uint16_t)(u >> 16);
}
__device__ __forceinline__ float bf2f(uint16_t h) {
    return __builtin_bit_cast(float, (uint32_t)h << 16);
}

__device__ __forceinline__ void async16(uint16_t* lds_dst, const uint16_t* g_src) {
    __builtin_amdgcn_global_load_lds(
        (const __attribute__((address_space(1))) void*)g_src,
        (__attribute__((address_space(3))) void*)lds_dst,
        16, 0, 0);
}

// ---------- weight prep: out[co][r] = bf16(in[r][col0+co]*scale), optional k-dup ----------
__global__ void wprep_k(const float* __restrict__ in, uint16_t* __restrict__ out,
                        int ld_in, int col0, float scale, int ldo, int dup) {
    int idx = blockIdx.x * 256 + threadIdx.x;          // over 512*512
    int co = idx >> 9, r = idx & 511;
    uint16_t v = f2bf(in[r * ld_in + col0 + co] * scale);
    out[co * ldo + r] = v;
    if (dup) out[co * ldo + 512 + r] = v;
}

// ---------- wv row-major convert: wv_rm[k][c'] = bf16(w_qkv[k][1024+c']) ----------
__global__ void wconv_k(const float* __restrict__ in, uint16_t* __restrict__ out) {
    int idx = blockIdx.x * 256 + threadIdx.x;
    int k = idx >> 9, c = idx & 511;
    out[k * 512 + c] = f2bf(in[k * 1536 + 1024 + c]);
}

// ---------- xt_k: x f32 -> xb (row-major bf16) + xT (transposed bf16 [b][512][4096]) ----------
__global__ __launch_bounds__(256, 4)
void xt_k(const float* __restrict__ x, uint16_t* __restrict__ xb, uint16_t* __restrict__ xT)
{
    __shared__ uint16_t lt[64 * 68];
    const int tid = threadIdx.x;
    const int bi = blockIdx.x;
    const int b = bi >> 9;
    const int rem = bi & 511;
    const int st = rem >> 3, ct = rem & 7;     // 64-spatial x 64-chan tile
    const int c4 = (tid & 15) * 4;
#pragma unroll
    for (int rep = 0; rep < 4; ++rep) {
        int r = (tid >> 4) + rep * 16;
        long gs = (long)(b * 4096 + st * 64 + r) * 512 + ct * 64 + c4;
        float4 v = *(const float4*)(x + gs);
        uint16_t t[4];
        t[0] = f2bf(v.x); t[1] = f2bf(v.y); t[2] = f2bf(v.z); t[3] = f2bf(v.w);
        *(ushort4*)(xb + gs) = *(const ushort4*)t;
#pragma unroll
        for (int q = 0; q < 4; ++q) lt[r * 68 + c4 + q] = t[q];
    }
    __syncthreads();
    const int s4 = (tid & 15) * 4;
#pragma unroll
    for (int rep = 0; rep < 4; ++rep) {
        int c = (tid >> 4) + rep * 16;
        uint16_t t[4];
#pragma unroll
        for (int q = 0; q < 4; ++q) t[q] = lt[(s4 + q) * 68 + c];
        *(ushort4*)(xT + (long)(b * 512 + ct * 64 + c) * 4096 + st * 64 + s4) =
            *(const ushort4*)t;
    }
}

// ---------- g8: 256x256 tile, BK=64, 8-phase counted-vmcnt (verified R5) ----------
template<bool OUTF32>
__global__ __launch_bounds__(512, 2)
void g8_k(const uint16_t* __restrict__ A, const uint16_t* __restrict__ Bt,
          void* __restrict__ Cp, const float* __restrict__ bias,
          int K, int lda, int ldb, int ldc, int mtiles, int ntiles,
          long abr, long bbe, long cbr)
{
    __shared__ uint16_t lds[65536];
    const int tid  = threadIdx.x;
    const int lane = tid & 63;
    const int wv   = tid >> 6;
    const int wr   = wv >> 2, wc = wv & 3;

    const int q8 = gridDim.x >> 3;
    const int l  = (blockIdx.x & 7) * q8 + (blockIdx.x >> 3);
    const int per   = mtiles * ntiles;
    const int batch = l / per;
    const int rem   = l - batch * per;
    const int mt    = rem / ntiles, nt = rem - mt * ntiles;

    const long arow0 = abr * batch + (long)mt * 256;
    const uint16_t* abase = A + arow0 * (long)lda;
    const uint16_t* btb   = Bt + bbe * batch + (long)nt * 256 * ldb;

    const int fr = lane & 15;
    const int cx0 = (((0 << 2) | (lane >> 4)) ^ (fr & 7)) * 8;
    const int cx1 = (((1 << 2) | (lane >> 4)) ^ (fr & 7)) * 8;
    const int baseA = wr * 8192 + fr * 64;
    const int baseB = (2 + (wc >> 1)) * 8192 + ((wc & 1) * 64 + fr) * 64;

    const int NT = K >> 6;

    auto stage = [&](int slot, const uint16_t* gb, int rstride, int k0) {
#pragma unroll
        for (int i = 0; i < 2; ++i) {
            int si = i * 512 + wv * 64 + lane;
            int rr = si >> 3, cc = (si & 7) ^ (rr & 7);
            async16(&lds[slot * 8192 + (i * 512 + wv * 64) * 8],
                    gb + (long)rr * rstride + k0 + cc * 8);
        }
    };

    f32x4 acc[8][4];
#pragma unroll
    for (int m = 0; m < 8; ++m)
#pragma unroll
        for (int n = 0; n < 4; ++n) acc[m][n] = (f32x4){0.f, 0.f, 0.f, 0.f};

    bf16x8 af[4], bfq[4];

    auto rdA = [&](int mb, int b4, int cx) {
#pragma unroll
        for (int mi = 0; mi < 4; ++mi)
            af[mi] = __builtin_bit_cast(bf16x8,
                *(const s16x8*)&lds[b4 * 8192 + baseA + (mb + mi) * 1024 + cx]);
    };
    auto rdB = [&](int b4, int cx) {
#pragma unroll
        for (int n = 0; n < 4; ++n)
            bfq[n] = __builtin_bit_cast(bf16x8,
                *(const s16x8*)&lds[b4 * 8192 + baseB + n * 1024 + cx]);
    };
    auto mm = [&](int mb) {
        asm volatile("s_waitcnt lgkmcnt(0)" ::: "memory");
        __builtin_amdgcn_sched_barrier(0);
        __builtin_amdgcn_s_setprio(1);
#pragma unroll
        for (int mi = 0; mi < 4; ++mi)
#pragma unroll
            for (int n = 0; n < 4; ++n)
                acc[mb + mi][n] = __builtin_amdgcn_mfma_f32_16x16x32_bf16(
                    af[mi], bfq[n], acc[mb + mi][n], 0, 0, 0);
        __builtin_amdgcn_s_setprio(0);
        __builtin_amdgcn_s_barrier();
    };

    stage(0, abase,              lda, 0);
    stage(1, abase + 128L * lda, lda, 0);
    stage(2, btb,                ldb, 0);
    stage(3, btb + 128L * ldb,   ldb, 0);
    stage(6, btb,                ldb, 64);
    stage(7, btb + 128L * ldb,   ldb, 64);
    asm volatile("s_waitcnt vmcnt(4)" ::: "memory");
    __builtin_amdgcn_sched_barrier(0);
    __builtin_amdgcn_s_barrier();

    for (int it = 0; it < (NT >> 1); ++it) {
        const int E = 2 * it, Od = E + 1;
        const bool s3 = (E + 2) < NT;
        const bool s7 = (Od + 2) < NT;
        const int kE2 = (E + 2) << 6, kO1 = Od << 6, kO2 = (Od + 2) << 6;

        rdB(0, cx0); rdA(0, 0, cx0);
        stage(4, abase,              lda, kO1);
        stage(5, abase + 128L * lda, lda, kO1);
        __builtin_amdgcn_s_barrier();
        mm(0);
        rdA(4, 0, cx0);
        __builtin_amdgcn_s_barrier();
        mm(4);
        rdB(0, cx1); rdA(0, 0, cx1);
        __builtin_amdgcn_s_barrier();
        mm(0);
        rdA(4, 0, cx1);
        if (s3) {
            stage(2, btb,              ldb, kE2);
            stage(3, btb + 128L * ldb, ldb, kE2);
            asm volatile("s_waitcnt vmcnt(4)" ::: "memory");
        } else {
            asm volatile("s_waitcnt vmcnt(0)" ::: "memory");
        }
        __builtin_amdgcn_sched_barrier(0);
        __builtin_amdgcn_s_barrier();
        mm(4);
        rdB(4, cx0); rdA(0, 4, cx0);
        if (s3) {
            stage(0, abase,              lda, kE2);
            stage(1, abase + 128L * lda, lda, kE2);
        }
        __builtin_amdgcn_s_barrier();
        mm(0);
        rdA(4, 4, cx0);
        __builtin_amdgcn_s_barrier();
        mm(4);
        rdB(4, cx1); rdA(0, 4, cx1);
        __builtin_amdgcn_s_barrier();
        mm(0);
        rdA(4, 4, cx1);
        if (s7) {
            stage(6, btb,              ldb, kO2);
            stage(7, btb + 128L * ldb, ldb, kO2);
            asm volatile("s_waitcnt vmcnt(4)" ::: "memory");
        } else {
            asm volatile("s_waitcnt vmcnt(0)" ::: "memory");
        }
        __builtin_amdgcn_sched_barrier(0);
        __builtin_amdgcn_s_barrier();
        mm(4);
    }

    const long crow0 = cbr * batch + (long)mt * 256 + wr * 128;
    const int  col0  = nt * 256 + wc * 64;
    float bv[4];
#pragma unroll
    for (int n = 0; n < 4; ++n)
        bv[n] = bias ? bias[col0 + n * 16 + (lane & 15)] : 0.f;
#pragma unroll
    for (int m = 0; m < 8; ++m) {
#pragma unroll
        for (int r = 0; r < 4; ++r) {
            long row = crow0 + m * 16 + (lane >> 4) * 4 + r;
#pragma unroll
            for (int n = 0; n < 4; ++n) {
                int col = col0 + n * 16 + (lane & 15);
                float v = acc[m][n][r];
                if constexpr (OUTF32)
                    ((float*)Cp)[row * (long)ldc + col] = v + bv[n];
                else
                    ((uint16_t*)Cp)[row * (long)ldc + col] = f2bf(v);
            }
        }
    }
}

// ---------- g8G: Gcat[b][m][z*512+n] = sum_k xT[b][m][zK+k]*xT[b][n][zK+k] ----------
__global__ __launch_bounds__(512, 2)
void g8G_k(const uint16_t* __restrict__ X, uint16_t* __restrict__ Gcat)
{
    __shared__ uint16_t lds[65536];
    const int tid  = threadIdx.x;
    const int lane = tid & 63;
    const int wv   = tid >> 6;
    const int wr   = wv >> 2, wc = wv & 3;

    const int q8 = gridDim.x >> 3;
    const int l  = (blockIdx.x & 7) * q8 + (blockIdx.x >> 3);
    const int bz = l >> 2;
    const int rem = l & 3;
    const int mt = rem >> 1, nt = rem & 1;
    const int b = bz >> 1, z = bz & 1;

    const uint16_t* xb0 = X + (long)b * 512 * 4096 + z * 2048;
    const uint16_t* abase = xb0 + (long)mt * 256 * 4096;
    const uint16_t* btb   = xb0 + (long)nt * 256 * 4096;

    const int fr = lane & 15;
    const int cx0 = (((0 << 2) | (lane >> 4)) ^ (fr & 7)) * 8;
    const int cx1 = (((1 << 2) | (lane >> 4)) ^ (fr & 7)) * 8;
    const int baseA = wr * 8192 + fr * 64;
    const int baseB = (2 + (wc >> 1)) * 8192 + ((wc & 1) * 64 + fr) * 64;

    const int NT = 32;   // K=2048

    auto stage = [&](int slot, const uint16_t* gb, int k0) {
#pragma unroll
        for (int i = 0; i < 2; ++i) {
            int si = i * 512 + wv * 64 + lane;
            int rr = si >> 3, cc = (si & 7) ^ (rr & 7);
            async16(&lds[slot * 8192 + (i * 512 + wv * 64) * 8],
                    gb + (long)rr * 4096 + k0 + cc * 8);
        }
    };

    f32x4 acc[8][4];
#pragma unroll
    for (int m = 0; m < 8; ++m)
#pragma unroll
        for (int n = 0; n < 4; ++n) acc[m][n] = (f32x4){0.f, 0.f, 0.f, 0.f};

    bf16x8 af[4], bfq[4];
    auto rdA = [&](int mb, int b4, int cx) {
#pragma unroll
        for (int mi = 0; mi < 4; ++mi)
            af[mi] = __builtin_bit_cast(bf16x8,
                *(const s16x8*)&lds[b4 * 8192 + baseA + (mb + mi) * 1024 + cx]);
    };
    auto rdB = [&](int b4, int cx) {
#pragma unroll
        for (int n = 0; n < 4; ++n)
            bfq[n] = __builtin_bit_cast(bf16x8,
                *(const s16x8*)&lds[b4 * 8192 + baseB + n * 1024 + cx]);
    };
    auto mm = [&](int mb) {
        asm volatile("s_waitcnt lgkmcnt(0)" ::: "memory");
        __builtin_amdgcn_sched_barrier(0);
        __builtin_amdgcn_s_setprio(1);
#pragma unroll
        for (int mi = 0; mi < 4; ++mi)
#pragma unroll
            for (int n = 0; n < 4; ++n)
                acc[mb + mi][n] = __builtin_amdgcn_mfma_f32_16x16x32_bf16(
                    af[mi], bfq[n], acc[mb + mi][n], 0, 0, 0);
        __builtin_amdgcn_s_setprio(0);
        __builtin_amdgcn_s_barrier();
    };

    stage(0, abase,               0);
    stage(1, abase + 128L * 4096, 0);
    stage(2, btb,                 0);
    stage(3, btb + 128L * 4096,   0);
    stage(6, btb,                 64);
    stage(7, btb + 128L * 4096,   64);
    asm volatile("s_waitcnt vmcnt(4)" ::: "memory");
    __builtin_amdgcn_sched_barrier(0);
    __builtin_amdgcn_s_barrier();

    for (int it = 0; it < (NT >> 1); ++it) {
        const int E = 2 * it, Od = E + 1;
        const bool s3 = (E + 2) < NT;
        const bool s7 = (Od + 2) < NT;
        const int kE2 = (E + 2) << 6, kO1 = Od << 6, kO2 = (Od + 2) << 6;

        rdB(0, cx0); rdA(0, 0, cx0);
        stage(4, abase,               kO1);
        stage(5, abase + 128L * 4096, kO1);
        __builtin_amdgcn_s_barrier();
        mm(0);
        rdA(4, 0, cx0);
        __builtin_amdgcn_s_barrier();
        mm(4);
        rdB(0, cx1); rdA(0, 0, cx1);
        __builtin_amdgcn_s_barrier();
        mm(0);
        rdA(4, 0, cx1);
        if (s3) {
            stage(2, btb,               kE2);
            stage(3, btb + 128L * 4096, kE2);
            asm volatile("s_waitcnt vmcnt(4)" ::: "memory");
        } else {
            asm volatile("s_waitcnt vmcnt(0)" ::: "memory");
        }
        __builtin_amdgcn_sched_barrier(0);
        __builtin_amdgcn_s_barrier();
        mm(4);
        rdB(4, cx0); rdA(0, 4, cx0);
        if (s3) {
            stage(0, abase,               kE2);
            stage(1, abase + 128L * 4096, kE2);
        }
        __builtin_amdgcn_s_barrier();
        mm(0);
        rdA(4, 4, cx0);
        __builtin_amdgcn_s_barrier();
        mm(4);
        rdB(4, cx1); rdA(0, 4, cx1);
        __builtin_amdgcn_s_barrier();
        mm(0);
        rdA(4, 4, cx1);
        if (s7) {
            stage(6, btb,               kO2);
            stage(7, btb + 128L * 4096, kO2);
            asm volatile("s_waitcnt vmcnt(4)" ::: "memory");
        } else {
            asm volatile("s_waitcnt vmcnt(0)" ::: "memory");
        }
        __builtin_amdgcn_sched_barrier(0);
        __builtin_amdgcn_s_barrier();
        mm(4);
    }

    uint16_t* o = Gcat + (long)b * 524288;
    const int row0 = mt * 256 + wr * 128;
    const int col0 = z * 512 + nt * 256 + wc * 64;
#pragma unroll
    for (int m = 0; m < 8; ++m)
#pragma unroll
        for (int r = 0; r < 4; ++r) {
            int row = row0 + m * 16 + (lane >> 4) * 4 + r;
#pragma unroll
            for (int n = 0; n < 4; ++n)
                o[(long)row * 1024 + col0 + n * 16 + (lane & 15)] = f2bf(acc[m][n][r]);
        }
}

// ---------- simfull: per (b,h): T1t = WkT·G (K=1024 cat) -> sim = WqTs·T1t -> softmax ----------
// T1t stored hi/lo split-bf16 (two LDS planes) so stage2 sees ~f32 precision.
__global__ __launch_bounds__(512, 1)
void simfull_k(const uint16_t* __restrict__ Gcat, const uint16_t* __restrict__ wkTcat,
               const uint16_t* __restrict__ wqTs, uint16_t* __restrict__ attnT)
{
    __shared__ uint16_t sm[73728];   // 147,456 B: T1hi[0,32768) T1lo[32768,65536) red[65536,73728)
    const int tid  = threadIdx.x;
    const int lane = tid & 63;
    const int wv   = tid >> 6;
    const int fr   = lane & 15;
    const int bi = blockIdx.x;
    const int h = bi >> 5;
    const int b = (bi & 7) * 4 + ((bi >> 3) & 3);   // same-b blocks share an XCD

    const uint16_t* gb  = Gcat + (long)b * 524288;        // [512][1024] bf16
    const uint16_t* ab  = wkTcat + (long)h * 64 * 1024;   // rows h*64..
    const uint16_t* qb2 = wqTs + (long)h * 64 * 512;      // BUG FIX: head offset

    f32x4 acc[4][4];
#pragma unroll
    for (int mf = 0; mf < 4; ++mf)
#pragma unroll
        for (int nf = 0; nf < 4; ++nf) acc[mf][nf] = (f32x4){0.f, 0.f, 0.f, 0.f};

    // ---- stage1: T1t[j][c] = sum_{c'} wkT[h*64+j][c'] * G[c][c'], K=1024 ----
    // staging: G rows (per-wave 64) at sm[0..32768), wkT 64 rows at sm[32768..36864)
    for (int t = 0; t < 16; ++t) {
        const int k0 = t * 64;
#pragma unroll
        for (int i = 0; i < 8; ++i) {
            int si = i * 64 + lane;
            int rr = si >> 3, cc = (si & 7) ^ (rr & 7);
            async16(&sm[wv * 4096 + i * 512],
                    gb + (long)(wv * 64 + rr) * 1024 + k0 + cc * 8);
        }
        {
            int rr = wv * 8 + (lane >> 3);
            int cc = (lane & 7) ^ (rr & 7);
            async16(&sm[32768 + wv * 512],
                    ab + (long)rr * 1024 + k0 + cc * 8);
        }
        asm volatile("s_waitcnt vmcnt(0)" ::: "memory");
        __syncthreads();
#pragma unroll
        for (int ks = 0; ks < 2; ++ks) {
            bf16x8 af[4], bfq[4];
            int cx = ((ks * 4 + (lane >> 4)) ^ (fr & 7)) * 8;
#pragma unroll
            for (int mf = 0; mf < 4; ++mf)
                af[mf] = __builtin_bit_cast(bf16x8,
                    *(const s16x8*)&sm[32768 + (mf * 16 + fr) * 64 + cx]);
#pragma unroll
            for (int nf = 0; nf < 4; ++nf)
                bfq[nf] = __builtin_bit_cast(bf16x8,
                    *(const s16x8*)&sm[(wv * 64 + nf * 16 + fr) * 64 + cx]);
#pragma unroll
            for (int mf = 0; mf < 4; ++mf)
#pragma unroll
                for (int nf = 0; nf < 4; ++nf)
                    acc[mf][nf] = __builtin_amdgcn_mfma_f32_16x16x32_bf16(
                        af[mf], bfq[nf], acc[mf][nf], 0, 0, 0);
        }
        __syncthreads();
    }

    // ---- write T1t hi/lo bf16 [64 j][512 c], chunk-XOR swizzled ----
#pragma unroll
    for (int mf = 0; mf < 4; ++mf)
#pragma unroll
        for (int nf = 0; nf < 4; ++nf)
#pragma unroll
            for (int r = 0; r < 4; ++r) {
                int j = mf * 16 + (lane >> 4) * 4 + r;
                int c = wv * 64 + nf * 16 + fr;
                float v = acc[mf][nf][r];
                uint16_t hi = f2bf(v);
                int off = j * 512 + ((c >> 3) ^ (j & 7)) * 8 + (c & 7);
                sm[off] = hi;
                sm[32768 + off] = f2bf(v - bf2f(hi));
            }
    __syncthreads();

    // ---- stage2: sim partial over c-slice [wv*64, wv*64+64), hi + lo ----
    f32x4 a2[4][4];
#pragma unroll
    for (int mf = 0; mf < 4; ++mf)
#pragma unroll
        for (int nf = 0; nf < 4; ++nf) a2[mf][nf] = (f32x4){0.f, 0.f, 0.f, 0.f};
#pragma unroll
    for (int ks = 0; ks < 2; ++ks) {
        bf16x8 af[4], bh[4], bl[4];
#pragma unroll
        for (int mf = 0; mf < 4; ++mf)
            af[mf] = __builtin_bit_cast(bf16x8,
                *(const s16x8*)&qb2[(long)(mf * 16 + fr) * 512 + wv * 64 + ks * 32 + (lane >> 4) * 8]);
#pragma unroll
        for (int nf = 0; nf < 4; ++nf) {
            int j = nf * 16 + fr;
            int ch = (wv * 8 + ks * 4 + (lane >> 4)) ^ (fr & 7);
            bh[nf] = __builtin_bit_cast(bf16x8, *(const s16x8*)&sm[j * 512 + ch * 8]);
            bl[nf] = __builtin_bit_cast(bf16x8, *(const s16x8*)&sm[32768 + j * 512 + ch * 8]);
        }
#pragma unroll
        for (int mf = 0; mf < 4; ++mf)
#pragma unroll
            for (int nf = 0; nf < 4; ++nf) {
                a2[mf][nf] = __builtin_amdgcn_mfma_f32_16x16x32_bf16(
                    af[mf], bh[nf], a2[mf][nf], 0, 0, 0);
                a2[mf][nf] = __builtin_amdgcn_mfma_f32_16x16x32_bf16(
                    af[mf], bl[nf], a2[mf][nf], 0, 0, 0);
            }
    }

    // ---- reduce partials across 8 waves into red[64][64] f32 ----
    float* red = (float*)&sm[65536];
    for (int w = 0; w < 8; ++w) {
        if (wv == w) {
#pragma unroll
            for (int mf = 0; mf < 4; ++mf)
#pragma unroll
                for (int nf = 0; nf < 4; ++nf)
#pragma unroll
                    for (int r = 0; r < 4; ++r) {
                        int i = mf * 16 + (lane >> 4) * 4 + r;
                        int j = nf * 16 + fr;
                        float* p = &red[i * 64 + j];
                        *p = (w == 0) ? a2[mf][nf][r] : (*p + a2[mf][nf][r]);
                    }
        }
        __syncthreads();
    }

    // ---- softmax over j (scale already folded into wqTs) ----
    float* rt1 = (float*)&sm[0];
    float* rt2 = (float*)&sm[512];
    const int i = tid >> 2, jc = tid & 3;
    float s[16];
    if (tid < 256) {
#pragma unroll
        for (int jj = 0; jj < 16; ++jj) s[jj] = red[i * 64 + jc * 16 + jj];
        float mx = s[0];
#pragma unroll
        for (int jj = 1; jj < 16; ++jj) mx = fmaxf(mx, s[jj]);
        rt1[i * 4 + jc] = mx;
    }
    __syncthreads();
    if (tid < 256) {
        float m4 = fmaxf(fmaxf(rt1[i * 4], rt1[i * 4 + 1]),
                         fmaxf(rt1[i * 4 + 2], rt1[i * 4 + 3]));
        float sum = 0.f;
#pragma unroll
        for (int jj = 0; jj < 16; ++jj) { s[jj] = __expf(s[jj] - m4); sum += s[jj]; }
        rt2[i * 4 + jc] = sum;
    }
    __syncthreads();
    if (tid < 256) {
        float tot = rt2[i * 4] + rt2[i * 4 + 1] + rt2[i * 4 + 2] + rt2[i * 4 + 3];
        float inv = 1.f / tot;
        uint16_t* at = attnT + (long)(b * 8 + h) * 4096;
#pragma unroll
        for (int jj = 0; jj < 16; ++jj)
            at[(jc * 16 + jj) * 64 + i] = f2bf(s[jj] * inv);
    }
}

// ---------- w2: W2T[b][c][h*64+j] = sum_i attn[i][j]*w_out[h*64+i][c] ----------
__global__ __launch_bounds__(256, 1)
void w2_k(const uint16_t* __restrict__ attnT, const uint16_t* __restrict__ woutT,
          uint16_t* __restrict__ W2T)
{
    const int tid = threadIdx.x;
    const int lane = tid & 63, wv = tid >> 6;
    const int b = blockIdx.x >> 3, h = blockIdx.x & 7;
    const uint16_t* at = attnT + (long)blockIdx.x * 4096;

    bf16x8 bfrag[2][4];
#pragma unroll
    for (int ks = 0; ks < 2; ++ks)
#pragma unroll
        for (int nf = 0; nf < 4; ++nf) {
            s16x8 v = *(const s16x8*)&at[(nf * 16 + (lane & 15)) * 64 + ks * 32 + (lane >> 4) * 8];
            bfrag[ks][nf] = __builtin_bit_cast(bf16x8, v);
        }
    f32x4 acc[8][4];
#pragma unroll
    for (int mf = 0; mf < 8; ++mf)
#pragma unroll
        for (int nf = 0; nf < 4; ++nf) acc[mf][nf] = (f32x4){0.f, 0.f, 0.f, 0.f};
#pragma unroll
    for (int mf = 0; mf < 8; ++mf) {
        int c = wv * 128 + mf * 16 + (lane & 15);
#pragma unroll
        for (int ks = 0; ks < 2; ++ks) {
            s16x8 v = *(const s16x8*)&woutT[(long)c * 512 + h * 64 + ks * 32 + (lane >> 4) * 8];
            bf16x8 af = __builtin_bit_cast(bf16x8, v);
#pragma unroll
            for (int nf = 0; nf < 4; ++nf)
                acc[mf][nf] = __builtin_amdgcn_mfma_f32_16x16x32_bf16(
                    af, bfrag[ks][nf], acc[mf][nf], 0, 0, 0);
        }
    }
    uint16_t* o = W2T + (long)b * 512 * 512;
#pragma unroll
    for (int mf = 0; mf < 8; ++mf)
#pragma unroll
        for (int nf = 0; nf < 4; ++nf)
#pragma unroll
            for (int r = 0; r < 4; ++r) {
                int c = wv * 128 + mf * 16 + (lane >> 4) * 4 + r;
                int j = nf * 16 + (lane & 15);
                o[(long)c * 512 + h * 64 + j] = f2bf(acc[mf][nf][r]);
            }
}

// ---------- launcher ----------
extern "C" void kernel_launch(void* const* d_in, const int* in_sizes, int n_in,
                              void* d_out, int out_size, void* d_ws, size_t ws_size,
                              hipStream_t stream)
{
    const float* x     = (const float*)d_in[0];
    const float* w_qkv = (const float*)d_in[1];
    const float* w_out = (const float*)d_in[2];
    const float* b_out = (const float*)d_in[3];
    float* out = (float*)d_out;

    char* ws = (char*)d_ws;
    uint16_t* xb     = (uint16_t*)(ws);                     // 134,217,728
    uint16_t* xT     = (uint16_t*)(ws + 134217728L);        // 134,217,728
    uint16_t* Gcat   = (uint16_t*)(ws + 268435456L);        // 33,554,432  [32][512][1024]
    uint16_t* attnT  = (uint16_t*)(ws + 301989888L);        // 2,097,152
    uint16_t* W2T    = (uint16_t*)(ws + 304087040L);        // 16,777,216
    uint16_t* Bteff  = (uint16_t*)(ws + 320864256L);        // 33,554,432
    uint16_t* wqTs   = (uint16_t*)(ws + 354418688L);        // 524,288
    uint16_t* wkTcat = (uint16_t*)(ws + 354942976L);        // 1,048,576
    uint16_t* woutT  = (uint16_t*)(ws + 355991552L);        // 524,288
    uint16_t* wv_rm  = (uint16_t*)(ws + 356515840L);        // 524,288
    // total 357,040,128 B

    wprep_k<<<1024, 256, 0, stream>>>(w_qkv, wqTs, 1536, 0, 0.125f, 512, 0);
    wprep_k<<<1024, 256, 0, stream>>>(w_qkv, wkTcat, 1536, 512, 1.f, 1024, 1);
    wprep_k<<<1024, 256, 0, stream>>>(w_out, woutT, 512, 0, 1.f, 512, 0);
    wconv_k<<<1024, 256, 0, stream>>>(w_qkv, wv_rm);

    // x -> xb (row-major bf16) + xT (channel-major bf16)
    xt_k<<<16384, 256, 0, stream>>>(x, xb, xT);

    // Gram: Gcat[b][m][z*512+n] (2-way K-split along spatial)
    g8G_k<<<256, 512, 0, stream>>>(xT, Gcat);

    // fused sim + softmax -> attnT
    simfull_k<<<256, 512, 0, stream>>>(Gcat, wkTcat, wqTs, attnT);

    // per-batch attention-projected weights
    w2_k<<<256, 256, 0, stream>>>(attnT, woutT, W2T);

    // Bteff[b][c][k] = sum_{c'} W2T[b][c][c'] * Wv[k][c']
    g8_k<false><<<128, 512, 0, stream>>>(
        W2T, wv_rm, Bteff, nullptr,
        512, 512, 512, 512, 2, 2, 512L, 0L, 512L);

    // out[b] = xb[b] @ Bteff[b]^T + b_out
    g8_k<true><<<1024, 512, 0, stream>>>(
        xb, Bteff, out, b_out,
        512, 512, 512, 512, 16, 2, 4096L, 262144L, 4096L);
}

// Round 8
// 379.405 us; speedup vs baseline: 1.6904x; 1.0071x over previous
//
#include <hip/hip_runtime.h>
#include <hip/hip_bf16.h>
#include <stdint.h>

// ---------- types ----------
using bf16x8 = __attribute__((ext_vector_type(8))) __bf16;
using s16x8  = __attribute__((ext_vector_type(8))) short;
using f32x4  = __attribute__((ext_vector_type(4))) float;

__device__ __forceinline__ uint16_t f2bf(float f) {
    uint32_t u = __builtin_bit_cast(uint32_t, f);
    u += 0x7fffu + ((u >> 16) & 1u);   // RNE
    return (uint16_t)(u >> 16);
}
__device__ __forceinline__ float bf2f(uint16_t h) {
    return __builtin_bit_cast(float, (uint32_t)h << 16);
}

__device__ __forceinline__ void async16(uint16_t* lds_dst, const uint16_t* g_src) {
    __builtin_amdgcn_global_load_lds(
        (const __attribute__((address_space(1))) void*)g_src,
        (__attribute__((address_space(3))) void*)lds_dst,
        16, 0, 0);
}

// ---------- merged weight prep (4 sections x 1024 blocks) ----------
__global__ void wprep_all(const float* __restrict__ wqkv, const float* __restrict__ wout,
                          uint16_t* __restrict__ wqTs, uint16_t* __restrict__ wkTcat,
                          uint16_t* __restrict__ woutT, uint16_t* __restrict__ wv_rm)
{
    int sec = blockIdx.x >> 10;
    int idx = (blockIdx.x & 1023) * 256 + threadIdx.x;   // over 512*512
    int co = idx >> 9, r = idx & 511;
    if (sec == 0) {
        wqTs[co * 512 + r] = f2bf(wqkv[r * 1536 + co] * 0.125f);
    } else if (sec == 1) {
        uint16_t v = f2bf(wqkv[r * 1536 + 512 + co]);
        wkTcat[co * 1024 + r] = v;
        wkTcat[co * 1024 + 512 + r] = v;
    } else if (sec == 2) {
        woutT[co * 512 + r] = f2bf(wout[r * 512 + co]);
    } else {
        wv_rm[co * 512 + r] = f2bf(wqkv[co * 1536 + 1024 + r]);
    }
}

// ---------- xt_k: x f32 -> xb (row-major bf16) + xT (transposed bf16 [b][512][4096]) ----------
__global__ __launch_bounds__(256, 4)
void xt_k(const float* __restrict__ x, uint16_t* __restrict__ xb, uint16_t* __restrict__ xT)
{
    __shared__ uint16_t lt[64 * 68];
    const int tid = threadIdx.x;
    const int bi = blockIdx.x;
    const int b = bi >> 9;
    const int rem = bi & 511;
    const int st = rem >> 3, ct = rem & 7;     // 64-spatial x 64-chan tile
    const int c4 = (tid & 15) * 4;
#pragma unroll
    for (int rep = 0; rep < 4; ++rep) {
        int r = (tid >> 4) + rep * 16;
        long gs = (long)(b * 4096 + st * 64 + r) * 512 + ct * 64 + c4;
        float4 v = *(const float4*)(x + gs);
        uint16_t t[4];
        t[0] = f2bf(v.x); t[1] = f2bf(v.y); t[2] = f2bf(v.z); t[3] = f2bf(v.w);
        *(ushort4*)(xb + gs) = *(const ushort4*)t;
#pragma unroll
        for (int q = 0; q < 4; ++q) lt[r * 68 + c4 + q] = t[q];
    }
    __syncthreads();
    const int s4 = (tid & 15) * 4;
#pragma unroll
    for (int rep = 0; rep < 4; ++rep) {
        int c = (tid >> 4) + rep * 16;
        uint16_t t[4];
#pragma unroll
        for (int q = 0; q < 4; ++q) t[q] = lt[(s4 + q) * 68 + c];
        *(ushort4*)(xT + (long)(b * 512 + ct * 64 + c) * 4096 + st * 64 + s4) =
            *(const ushort4*)t;
    }
}

// ---------- g8: 256x256 tile, BK=64, 8-phase counted-vmcnt (verified R5/R7) ----------
template<bool OUTF32>
__global__ __launch_bounds__(512, 2)
void g8_k(const uint16_t* __restrict__ A, const uint16_t* __restrict__ Bt,
          void* __restrict__ Cp, const float* __restrict__ bias,
          int K, int lda, int ldb, int ldc, int mtiles, int ntiles,
          long abr, long bbe, long cbr)
{
    __shared__ uint16_t lds[65536];
    const int tid  = threadIdx.x;
    const int lane = tid & 63;
    const int wv   = tid >> 6;
    const int wr   = wv >> 2, wc = wv & 3;

    const int q8 = gridDim.x >> 3;
    const int l  = (blockIdx.x & 7) * q8 + (blockIdx.x >> 3);
    const int per   = mtiles * ntiles;
    const int batch = l / per;
    const int rem   = l - batch * per;
    const int mt    = rem / ntiles, nt = rem - mt * ntiles;

    const long arow0 = abr * batch + (long)mt * 256;
    const uint16_t* abase = A + arow0 * (long)lda;
    const uint16_t* btb   = Bt + bbe * batch + (long)nt * 256 * ldb;

    const int fr = lane & 15;
    const int cx0 = (((0 << 2) | (lane >> 4)) ^ (fr & 7)) * 8;
    const int cx1 = (((1 << 2) | (lane >> 4)) ^ (fr & 7)) * 8;
    const int baseA = wr * 8192 + fr * 64;
    const int baseB = (2 + (wc >> 1)) * 8192 + ((wc & 1) * 64 + fr) * 64;

    const int NT = K >> 6;

    auto stage = [&](int slot, const uint16_t* gb, int rstride, int k0) {
#pragma unroll
        for (int i = 0; i < 2; ++i) {
            int si = i * 512 + wv * 64 + lane;
            int rr = si >> 3, cc = (si & 7) ^ (rr & 7);
            async16(&lds[slot * 8192 + (i * 512 + wv * 64) * 8],
                    gb + (long)rr * rstride + k0 + cc * 8);
        }
    };

    f32x4 acc[8][4];
#pragma unroll
    for (int m = 0; m < 8; ++m)
#pragma unroll
        for (int n = 0; n < 4; ++n) acc[m][n] = (f32x4){0.f, 0.f, 0.f, 0.f};

    bf16x8 af[4], bfq[4];

    auto rdA = [&](int mb, int b4, int cx) {
#pragma unroll
        for (int mi = 0; mi < 4; ++mi)
            af[mi] = __builtin_bit_cast(bf16x8,
                *(const s16x8*)&lds[b4 * 8192 + baseA + (mb + mi) * 1024 + cx]);
    };
    auto rdB = [&](int b4, int cx) {
#pragma unroll
        for (int n = 0; n < 4; ++n)
            bfq[n] = __builtin_bit_cast(bf16x8,
                *(const s16x8*)&lds[b4 * 8192 + baseB + n * 1024 + cx]);
    };
    auto mm = [&](int mb) {
        asm volatile("s_waitcnt lgkmcnt(0)" ::: "memory");
        __builtin_amdgcn_sched_barrier(0);
        __builtin_amdgcn_s_setprio(1);
#pragma unroll
        for (int mi = 0; mi < 4; ++mi)
#pragma unroll
            for (int n = 0; n < 4; ++n)
                acc[mb + mi][n] = __builtin_amdgcn_mfma_f32_16x16x32_bf16(
                    af[mi], bfq[n], acc[mb + mi][n], 0, 0, 0);
        __builtin_amdgcn_s_setprio(0);
        __builtin_amdgcn_s_barrier();
    };

    stage(0, abase,              lda, 0);
    stage(1, abase + 128L * lda, lda, 0);
    stage(2, btb,                ldb, 0);
    stage(3, btb + 128L * ldb,   ldb, 0);
    stage(6, btb,                ldb, 64);
    stage(7, btb + 128L * ldb,   ldb, 64);
    asm volatile("s_waitcnt vmcnt(4)" ::: "memory");
    __builtin_amdgcn_sched_barrier(0);
    __builtin_amdgcn_s_barrier();

    for (int it = 0; it < (NT >> 1); ++it) {
        const int E = 2 * it, Od = E + 1;
        const bool s3 = (E + 2) < NT;
        const bool s7 = (Od + 2) < NT;
        const int kE2 = (E + 2) << 6, kO1 = Od << 6, kO2 = (Od + 2) << 6;

        rdB(0, cx0); rdA(0, 0, cx0);
        stage(4, abase,              lda, kO1);
        stage(5, abase + 128L * lda, lda, kO1);
        __builtin_amdgcn_s_barrier();
        mm(0);
        rdA(4, 0, cx0);
        __builtin_amdgcn_s_barrier();
        mm(4);
        rdB(0, cx1); rdA(0, 0, cx1);
        __builtin_amdgcn_s_barrier();
        mm(0);
        rdA(4, 0, cx1);
        if (s3) {
            stage(2, btb,              ldb, kE2);
            stage(3, btb + 128L * ldb, ldb, kE2);
            asm volatile("s_waitcnt vmcnt(4)" ::: "memory");
        } else {
            asm volatile("s_waitcnt vmcnt(0)" ::: "memory");
        }
        __builtin_amdgcn_sched_barrier(0);
        __builtin_amdgcn_s_barrier();
        mm(4);
        rdB(4, cx0); rdA(0, 4, cx0);
        if (s3) {
            stage(0, abase,              lda, kE2);
            stage(1, abase + 128L * lda, lda, kE2);
        }
        __builtin_amdgcn_s_barrier();
        mm(0);
        rdA(4, 4, cx0);
        __builtin_amdgcn_s_barrier();
        mm(4);
        rdB(4, cx1); rdA(0, 4, cx1);
        __builtin_amdgcn_s_barrier();
        mm(0);
        rdA(4, 4, cx1);
        if (s7) {
            stage(6, btb,              ldb, kO2);
            stage(7, btb + 128L * ldb, ldb, kO2);
            asm volatile("s_waitcnt vmcnt(4)" ::: "memory");
        } else {
            asm volatile("s_waitcnt vmcnt(0)" ::: "memory");
        }
        __builtin_amdgcn_sched_barrier(0);
        __builtin_amdgcn_s_barrier();
        mm(4);
    }

    const long crow0 = cbr * batch + (long)mt * 256 + wr * 128;
    const int  col0  = nt * 256 + wc * 64;
    float bv[4];
#pragma unroll
    for (int n = 0; n < 4; ++n)
        bv[n] = bias ? bias[col0 + n * 16 + (lane & 15)] : 0.f;
#pragma unroll
    for (int m = 0; m < 8; ++m) {
#pragma unroll
        for (int r = 0; r < 4; ++r) {
            long row = crow0 + m * 16 + (lane >> 4) * 4 + r;
#pragma unroll
            for (int n = 0; n < 4; ++n) {
                int col = col0 + n * 16 + (lane & 15);
                float v = acc[m][n][r];
                if constexpr (OUTF32)
                    ((float*)Cp)[row * (long)ldc + col] = v + bv[n];
                else
                    ((uint16_t*)Cp)[row * (long)ldc + col] = f2bf(v);
            }
        }
    }
}

// ---------- g8G: Gram with symmetry — 3 quadrants per (b,z), mirror off-diag ----------
// Gcat[b][c][z*512+c'] = sum_k xT[b][c][zK+k]*xT[b][c'][zK+k]; symmetric per z.
__global__ __launch_bounds__(512, 2)
void g8G_k(const uint16_t* __restrict__ X, uint16_t* __restrict__ Gcat)
{
    __shared__ uint16_t lds[65536];
    const int tid  = threadIdx.x;
    const int lane = tid & 63;
    const int wv   = tid >> 6;
    const int wr   = wv >> 2, wc = wv & 3;

    // XCD swizzle (grid=192, %8==0): q8=24, consecutive l share (b,z)
    const int q8 = gridDim.x >> 3;
    const int l  = (blockIdx.x & 7) * q8 + (blockIdx.x >> 3);
    const int g  = l / 3;
    const int quad = l - g * 3;                  // 0:(0,0) 1:(1,1) 2:(0,1)
    const int b = g >> 1, z = g & 1;
    const int mt = (quad == 1) ? 1 : 0;
    const int nt = (quad == 0) ? 0 : 1;

    const uint16_t* xb0 = X + (long)b * 512 * 4096 + z * 2048;
    const uint16_t* abase = xb0 + (long)mt * 256 * 4096;
    const uint16_t* btb   = xb0 + (long)nt * 256 * 4096;

    const int fr = lane & 15;
    const int cx0 = (((0 << 2) | (lane >> 4)) ^ (fr & 7)) * 8;
    const int cx1 = (((1 << 2) | (lane >> 4)) ^ (fr & 7)) * 8;
    const int baseA = wr * 8192 + fr * 64;
    const int baseB = (2 + (wc >> 1)) * 8192 + ((wc & 1) * 64 + fr) * 64;

    const int NT = 32;   // K=2048

    auto stage = [&](int slot, const uint16_t* gb, int k0) {
#pragma unroll
        for (int i = 0; i < 2; ++i) {
            int si = i * 512 + wv * 64 + lane;
            int rr = si >> 3, cc = (si & 7) ^ (rr & 7);
            async16(&lds[slot * 8192 + (i * 512 + wv * 64) * 8],
                    gb + (long)rr * 4096 + k0 + cc * 8);
        }
    };

    f32x4 acc[8][4];
#pragma unroll
    for (int m = 0; m < 8; ++m)
#pragma unroll
        for (int n = 0; n < 4; ++n) acc[m][n] = (f32x4){0.f, 0.f, 0.f, 0.f};

    bf16x8 af[4], bfq[4];
    auto rdA = [&](int mb, int b4, int cx) {
#pragma unroll
        for (int mi = 0; mi < 4; ++mi)
            af[mi] = __builtin_bit_cast(bf16x8,
                *(const s16x8*)&lds[b4 * 8192 + baseA + (mb + mi) * 1024 + cx]);
    };
    auto rdB = [&](int b4, int cx) {
#pragma unroll
        for (int n = 0; n < 4; ++n)
            bfq[n] = __builtin_bit_cast(bf16x8,
                *(const s16x8*)&lds[b4 * 8192 + baseB + n * 1024 + cx]);
    };
    auto mm = [&](int mb) {
        asm volatile("s_waitcnt lgkmcnt(0)" ::: "memory");
        __builtin_amdgcn_sched_barrier(0);
        __builtin_amdgcn_s_setprio(1);
#pragma unroll
        for (int mi = 0; mi < 4; ++mi)
#pragma unroll
            for (int n = 0; n < 4; ++n)
                acc[mb + mi][n] = __builtin_amdgcn_mfma_f32_16x16x32_bf16(
                    af[mi], bfq[n], acc[mb + mi][n], 0, 0, 0);
        __builtin_amdgcn_s_setprio(0);
        __builtin_amdgcn_s_barrier();
    };

    stage(0, abase,               0);
    stage(1, abase + 128L * 4096, 0);
    stage(2, btb,                 0);
    stage(3, btb + 128L * 4096,   0);
    stage(6, btb,                 64);
    stage(7, btb + 128L * 4096,   64);
    asm volatile("s_waitcnt vmcnt(4)" ::: "memory");
    __builtin_amdgcn_sched_barrier(0);
    __builtin_amdgcn_s_barrier();

    for (int it = 0; it < (NT >> 1); ++it) {
        const int E = 2 * it, Od = E + 1;
        const bool s3 = (E + 2) < NT;
        const bool s7 = (Od + 2) < NT;
        const int kE2 = (E + 2) << 6, kO1 = Od << 6, kO2 = (Od + 2) << 6;

        rdB(0, cx0); rdA(0, 0, cx0);
        stage(4, abase,               kO1);
        stage(5, abase + 128L * 4096, kO1);
        __builtin_amdgcn_s_barrier();
        mm(0);
        rdA(4, 0, cx0);
        __builtin_amdgcn_s_barrier();
        mm(4);
        rdB(0, cx1); rdA(0, 0, cx1);
        __builtin_amdgcn_s_barrier();
        mm(0);
        rdA(4, 0, cx1);
        if (s3) {
            stage(2, btb,               kE2);
            stage(3, btb + 128L * 4096, kE2);
            asm volatile("s_waitcnt vmcnt(4)" ::: "memory");
        } else {
            asm volatile("s_waitcnt vmcnt(0)" ::: "memory");
        }
        __builtin_amdgcn_sched_barrier(0);
        __builtin_amdgcn_s_barrier();
        mm(4);
        rdB(4, cx0); rdA(0, 4, cx0);
        if (s3) {
            stage(0, abase,               kE2);
            stage(1, abase + 128L * 4096, kE2);
        }
        __builtin_amdgcn_s_barrier();
        mm(0);
        rdA(4, 4, cx0);
        __builtin_amdgcn_s_barrier();
        mm(4);
        rdB(4, cx1); rdA(0, 4, cx1);
        __builtin_amdgcn_s_barrier();
        mm(0);
        rdA(4, 4, cx1);
        if (s7) {
            stage(6, btb,               kO2);
            stage(7, btb + 128L * 4096, kO2);
            asm volatile("s_waitcnt vmcnt(4)" ::: "memory");
        } else {
            asm volatile("s_waitcnt vmcnt(0)" ::: "memory");
        }
        __builtin_amdgcn_sched_barrier(0);
        __builtin_amdgcn_s_barrier();
        mm(4);
    }

    uint16_t* o = Gcat + (long)b * 524288;
    const int zoff = z * 512;
    const int row0 = mt * 256 + wr * 128;
    const int col0 = nt * 256 + wc * 64;
#pragma unroll
    for (int m = 0; m < 8; ++m) {
#pragma unroll
        for (int r = 0; r < 4; ++r) {
            int row = row0 + m * 16 + (lane >> 4) * 4 + r;
#pragma unroll
            for (int n = 0; n < 4; ++n)
                o[(long)row * 1024 + zoff + col0 + n * 16 + (lane & 15)] = f2bf(acc[m][n][r]);
        }
        if (quad == 2) {
            // mirror: element (row, col) -> (col, row); r-index contiguous -> ushort4
            int rbase = row0 + m * 16 + (lane >> 4) * 4;
#pragma unroll
            for (int n = 0; n < 4; ++n) {
                int col = col0 + n * 16 + (lane & 15);
                uint16_t t[4];
#pragma unroll
                for (int r = 0; r < 4; ++r) t[r] = f2bf(acc[m][n][r]);
                *(ushort4*)&o[(long)col * 1024 + zoff + rbase] = *(const ushort4*)t;
            }
        }
    }
}

// ---------- simfull: per (b,h): T1t = WkT·G (K=1024 cat) -> sim = WqTs·T1t -> softmax ----------
// T1t stored hi/lo split-bf16 (two LDS planes) so stage2 sees ~f32 precision.
__global__ __launch_bounds__(512, 1)
void simfull_k(const uint16_t* __restrict__ Gcat, const uint16_t* __restrict__ wkTcat,
               const uint16_t* __restrict__ wqTs, uint16_t* __restrict__ attnT)
{
    __shared__ uint16_t sm[73728];   // 147,456 B
    const int tid  = threadIdx.x;
    const int lane = tid & 63;
    const int wv   = tid >> 6;
    const int fr   = lane & 15;
    const int bi = blockIdx.x;
    const int h = bi >> 5;
    const int b = (bi & 7) * 4 + ((bi >> 3) & 3);   // same-b blocks share an XCD

    const uint16_t* gb  = Gcat + (long)b * 524288;
    const uint16_t* ab  = wkTcat + (long)h * 64 * 1024;
    const uint16_t* qb2 = wqTs + (long)h * 64 * 512;

    f32x4 acc[4][4];
#pragma unroll
    for (int mf = 0; mf < 4; ++mf)
#pragma unroll
        for (int nf = 0; nf < 4; ++nf) acc[mf][nf] = (f32x4){0.f, 0.f, 0.f, 0.f};

    for (int t = 0; t < 16; ++t) {
        const int k0 = t * 64;
#pragma unroll
        for (int i = 0; i < 8; ++i) {
            int si = i * 64 + lane;
            int rr = si >> 3, cc = (si & 7) ^ (rr & 7);
            async16(&sm[wv * 4096 + i * 512],
                    gb + (long)(wv * 64 + rr) * 1024 + k0 + cc * 8);
        }
        {
            int rr = wv * 8 + (lane >> 3);
            int cc = (lane & 7) ^ (rr & 7);
            async16(&sm[32768 + wv * 512],
                    ab + (long)rr * 1024 + k0 + cc * 8);
        }
        asm volatile("s_waitcnt vmcnt(0)" ::: "memory");
        __syncthreads();
#pragma unroll
        for (int ks = 0; ks < 2; ++ks) {
            bf16x8 af[4], bfq[4];
            int cx = ((ks * 4 + (lane >> 4)) ^ (fr & 7)) * 8;
#pragma unroll
            for (int mf = 0; mf < 4; ++mf)
                af[mf] = __builtin_bit_cast(bf16x8,
                    *(const s16x8*)&sm[32768 + (mf * 16 + fr) * 64 + cx]);
#pragma unroll
            for (int nf = 0; nf < 4; ++nf)
                bfq[nf] = __builtin_bit_cast(bf16x8,
                    *(const s16x8*)&sm[(wv * 64 + nf * 16 + fr) * 64 + cx]);
#pragma unroll
            for (int mf = 0; mf < 4; ++mf)
#pragma unroll
                for (int nf = 0; nf < 4; ++nf)
                    acc[mf][nf] = __builtin_amdgcn_mfma_f32_16x16x32_bf16(
                        af[mf], bfq[nf], acc[mf][nf], 0, 0, 0);
        }
        __syncthreads();
    }

#pragma unroll
    for (int mf = 0; mf < 4; ++mf)
#pragma unroll
        for (int nf = 0; nf < 4; ++nf)
#pragma unroll
            for (int r = 0; r < 4; ++r) {
                int j = mf * 16 + (lane >> 4) * 4 + r;
                int c = wv * 64 + nf * 16 + fr;
                float v = acc[mf][nf][r];
                uint16_t hi = f2bf(v);
                int off = j * 512 + ((c >> 3) ^ (j & 7)) * 8 + (c & 7);
                sm[off] = hi;
                sm[32768 + off] = f2bf(v - bf2f(hi));
            }
    __syncthreads();

    f32x4 a2[4][4];
#pragma unroll
    for (int mf = 0; mf < 4; ++mf)
#pragma unroll
        for (int nf = 0; nf < 4; ++nf) a2[mf][nf] = (f32x4){0.f, 0.f, 0.f, 0.f};
#pragma unroll
    for (int ks = 0; ks < 2; ++ks) {
        bf16x8 af[4], bh[4], bl[4];
#pragma unroll
        for (int mf = 0; mf < 4; ++mf)
            af[mf] = __builtin_bit_cast(bf16x8,
                *(const s16x8*)&qb2[(long)(mf * 16 + fr) * 512 + wv * 64 + ks * 32 + (lane >> 4) * 8]);
#pragma unroll
        for (int nf = 0; nf < 4; ++nf) {
            int j = nf * 16 + fr;
            int ch = (wv * 8 + ks * 4 + (lane >> 4)) ^ (fr & 7);
            bh[nf] = __builtin_bit_cast(bf16x8, *(const s16x8*)&sm[j * 512 + ch * 8]);
            bl[nf] = __builtin_bit_cast(bf16x8, *(const s16x8*)&sm[32768 + j * 512 + ch * 8]);
        }
#pragma unroll
        for (int mf = 0; mf < 4; ++mf)
#pragma unroll
            for (int nf = 0; nf < 4; ++nf) {
                a2[mf][nf] = __builtin_amdgcn_mfma_f32_16x16x32_bf16(
                    af[mf], bh[nf], a2[mf][nf], 0, 0, 0);
                a2[mf][nf] = __builtin_amdgcn_mfma_f32_16x16x32_bf16(
                    af[mf], bl[nf], a2[mf][nf], 0, 0, 0);
            }
    }

    float* red = (float*)&sm[65536];
    for (int w = 0; w < 8; ++w) {
        if (wv == w) {
#pragma unroll
            for (int mf = 0; mf < 4; ++mf)
#pragma unroll
                for (int nf = 0; nf < 4; ++nf)
#pragma unroll
                    for (int r = 0; r < 4; ++r) {
                        int i = mf * 16 + (lane >> 4) * 4 + r;
                        int j = nf * 16 + fr;
                        float* p = &red[i * 64 + j];
                        *p = (w == 0) ? a2[mf][nf][r] : (*p + a2[mf][nf][r]);
                    }
        }
        __syncthreads();
    }

    float* rt1 = (float*)&sm[0];
    float* rt2 = (float*)&sm[512];
    const int i = tid >> 2, jc = tid & 3;
    float s[16];
    if (tid < 256) {
#pragma unroll
        for (int jj = 0; jj < 16; ++jj) s[jj] = red[i * 64 + jc * 16 + jj];
        float mx = s[0];
#pragma unroll
        for (int jj = 1; jj < 16; ++jj) mx = fmaxf(mx, s[jj]);
        rt1[i * 4 + jc] = mx;
    }
    __syncthreads();
    if (tid < 256) {
        float m4 = fmaxf(fmaxf(rt1[i * 4], rt1[i * 4 + 1]),
                         fmaxf(rt1[i * 4 + 2], rt1[i * 4 + 3]));
        float sum = 0.f;
#pragma unroll
        for (int jj = 0; jj < 16; ++jj) { s[jj] = __expf(s[jj] - m4); sum += s[jj]; }
        rt2[i * 4 + jc] = sum;
    }
    __syncthreads();
    if (tid < 256) {
        float tot = rt2[i * 4] + rt2[i * 4 + 1] + rt2[i * 4 + 2] + rt2[i * 4 + 3];
        float inv = 1.f / tot;
        uint16_t* at = attnT + (long)(b * 8 + h) * 4096;
#pragma unroll
        for (int jj = 0; jj < 16; ++jj)
            at[(jc * 16 + jj) * 64 + i] = f2bf(s[jj] * inv);
    }
}

// ---------- w2: W2T[b][c][h*64+j] = sum_i attn[i][j]*w_out[h*64+i][c] ----------
__global__ __launch_bounds__(256, 1)
void w2_k(const uint16_t* __restrict__ attnT, const uint16_t* __restrict__ woutT,
          uint16_t* __restrict__ W2T)
{
    const int tid = threadIdx.x;
    const int lane = tid & 63, wv = tid >> 6;
    const int b = blockIdx.x >> 3, h = blockIdx.x & 7;
    const uint16_t* at = attnT + (long)blockIdx.x * 4096;

    bf16x8 bfrag[2][4];
#pragma unroll
    for (int ks = 0; ks < 2; ++ks)
#pragma unroll
        for (int nf = 0; nf < 4; ++nf) {
            s16x8 v = *(const s16x8*)&at[(nf * 16 + (lane & 15)) * 64 + ks * 32 + (lane >> 4) * 8];
            bfrag[ks][nf] = __builtin_bit_cast(bf16x8, v);
        }
    f32x4 acc[8][4];
#pragma unroll
    for (int mf = 0; mf < 8; ++mf)
#pragma unroll
        for (int nf = 0; nf < 4; ++nf) acc[mf][nf] = (f32x4){0.f, 0.f, 0.f, 0.f};
#pragma unroll
    for (int mf = 0; mf < 8; ++mf) {
        int c = wv * 128 + mf * 16 + (lane & 15);
#pragma unroll
        for (int ks = 0; ks < 2; ++ks) {
            s16x8 v = *(const s16x8*)&woutT[(long)c * 512 + h * 64 + ks * 32 + (lane >> 4) * 8];
            bf16x8 af = __builtin_bit_cast(bf16x8, v);
#pragma unroll
            for (int nf = 0; nf < 4; ++nf)
                acc[mf][nf] = __builtin_amdgcn_mfma_f32_16x16x32_bf16(
                    af, bfrag[ks][nf], acc[mf][nf], 0, 0, 0);
        }
    }
    uint16_t* o = W2T + (long)b * 512 * 512;
#pragma unroll
    for (int mf = 0; mf < 8; ++mf)
#pragma unroll
        for (int nf = 0; nf < 4; ++nf)
#pragma unroll
            for (int r = 0; r < 4; ++r) {
                int c = wv * 128 + mf * 16 + (lane >> 4) * 4 + r;
                int j = nf * 16 + (lane & 15);
                o[(long)c * 512 + h * 64 + j] = f2bf(acc[mf][nf][r]);
            }
}

// ---------- launcher ----------
extern "C" void kernel_launch(void* const* d_in, const int* in_sizes, int n_in,
                              void* d_out, int out_size, void* d_ws, size_t ws_size,
                              hipStream_t stream)
{
    const float* x     = (const float*)d_in[0];
    const float* w_qkv = (const float*)d_in[1];
    const float* w_out = (const float*)d_in[2];
    const float* b_out = (const float*)d_in[3];
    float* out = (float*)d_out;

    char* ws = (char*)d_ws;
    uint16_t* xb     = (uint16_t*)(ws);                     // 134,217,728
    uint16_t* xT     = (uint16_t*)(ws + 134217728L);        // 134,217,728
    uint16_t* Gcat   = (uint16_t*)(ws + 268435456L);        // 33,554,432  [32][512][1024]
    uint16_t* attnT  = (uint16_t*)(ws + 301989888L);        // 2,097,152
    uint16_t* W2T    = (uint16_t*)(ws + 304087040L);        // 16,777,216
    uint16_t* Bteff  = (uint16_t*)(ws + 320864256L);        // 33,554,432
    uint16_t* wqTs   = (uint16_t*)(ws + 354418688L);        // 524,288
    uint16_t* wkTcat = (uint16_t*)(ws + 354942976L);        // 1,048,576
    uint16_t* woutT  = (uint16_t*)(ws + 355991552L);        // 524,288
    uint16_t* wv_rm  = (uint16_t*)(ws + 356515840L);        // 524,288

    wprep_all<<<4096, 256, 0, stream>>>(w_qkv, w_out, wqTs, wkTcat, woutT, wv_rm);

    // x -> xb (row-major bf16) + xT (channel-major bf16)
    xt_k<<<16384, 256, 0, stream>>>(x, xb, xT);

    // Gram with symmetry: 3 quadrants per (b,z), mirrored epilogue
    g8G_k<<<192, 512, 0, stream>>>(xT, Gcat);

    // fused sim + softmax -> attnT
    simfull_k<<<256, 512, 0, stream>>>(Gcat, wkTcat, wqTs, attnT);

    // per-batch attention-projected weights
    w2_k<<<256, 256, 0, stream>>>(attnT, woutT, W2T);

    // Bteff[b][c][k] = sum_{c'} W2T[b][c][c'] * Wv[k][c']
    g8_k<false><<<128, 512, 0, stream>>>(
        W2T, wv_rm, Bteff, nullptr,
        512, 512, 512, 512, 2, 2, 512L, 0L, 512L);

    // out[b] = xb[b] @ Bteff[b]^T + b_out
    g8_k<true><<<1024, 512, 0, stream>>>(
        xb, Bteff, out, b_out,
        512, 512, 512, 512, 16, 2, 4096L, 262144L, 4096L);
}